// Round 4
// baseline (1914.415 us; speedup 1.0000x reference)
//
#include <hip/hip_runtime.h>

typedef unsigned short u16;
typedef unsigned int   u32;
typedef __attribute__((ext_vector_type(8))) short short8;
typedef __attribute__((ext_vector_type(4))) float f32x4;

struct __align__(8) u16x4 { u16 x, y, z, w; };

#define NL 7
#define M_DIM 131072              // B*S = 256*512

__device__ __forceinline__ float b2f(u16 u) {
  union { float f; u32 i; } c; c.i = ((u32)u) << 16; return c.f;
}
__device__ __forceinline__ u16 f2b(float f) {
  union { float f; u32 i; } c; c.f = f;
  u32 r = c.i + 0x7FFFu + ((c.i >> 16) & 1u);
  return (u16)(r >> 16);
}

// ---------------- weight conversion (fp32 -> bf16, transposed to [N][K]) ----------------

__global__ __launch_bounds__(256) void conv_w1_k(const float* __restrict__ w1, u16* __restrict__ wT) {
  int idx = blockIdx.x * 256 + threadIdx.x;            // NL*256*256 ; [i][n][k]
  int i = idx >> 16, rem = idx & 65535;
  int n = rem >> 8, k = rem & 255;
  wT[idx] = f2b(w1[(i << 16) + (k << 8) + n]);
}

__global__ __launch_bounds__(256) void conv_wd_k(const float* __restrict__ wd, u16* __restrict__ wT) {
  int idx = blockIdx.x * 256 + threadIdx.x;            // NL*256*512 ; [i][n][k2], k2=tap*256+k
  int i = idx / 131072, rem = idx & 131071;
  int n = rem >> 9, k2 = rem & 511;
  int tap = k2 >> 8, k = k2 & 255;
  wT[idx] = f2b(wd[(((i * 2 + tap) << 8) + k) * 256 + n]);
}

__global__ __launch_bounds__(256) void conv_weg_k(const float* __restrict__ we, const float* __restrict__ wg,
                                                  u16* __restrict__ wT) {
  int idx = blockIdx.x * 256 + threadIdx.x;            // NL*2*256*256 ; [i][src][n][k]
  int i = idx / 131072, rem = idx & 131071;
  int src = rem >> 16, n = (rem >> 8) & 255, k = rem & 255;
  const float* W = src ? wg : we;
  wT[idx] = f2b(W[((i << 8) + k) * 256 + n]);
}

__global__ __launch_bounds__(256) void conv_wo_k(const float* __restrict__ outW, u16* __restrict__ wTo) {
  int idx = blockIdx.x * 256 + threadIdx.x;            // 32*256 ; [v][k]
  int v = idx >> 8, k = idx & 255;
  wTo[idx] = f2b(outW[k * 32 + v]);
}

// ---------------- zlat = z @ latent_W + latent_b  [256,256] fp32 ----------------

__global__ __launch_bounds__(256) void zlat_k(const float* __restrict__ z, const float* __restrict__ W,
                                              const float* __restrict__ bias, float* __restrict__ zlat) {
  int b = blockIdx.x, c = threadIdx.x;
  float acc = bias[c];
  for (int l = 0; l < 256; ++l) acc += z[b * 256 + l] * W[l * 256 + c];
  zlat[b * 256 + c] = acc;
}

// ---------------- embed: h = bf16(emb[x] + zlat) ----------------

__global__ __launch_bounds__(256) void embed_k(const int* __restrict__ x, const float* __restrict__ emb,
                                               const float* __restrict__ zlat, u16* __restrict__ h) {
  int wave = threadIdx.x >> 6, lane = threadIdx.x & 63;
  int r = blockIdx.x * 4 + wave;
  int c = lane * 4;
  int tok = x[r];
  int bi = r >> 9;
  float4 ev = *(const float4*)&emb[tok * 256 + c];
  float4 zv = *(const float4*)&zlat[bi * 256 + c];
  u16x4 hb;
  hb.x = f2b(ev.x + zv.x); hb.y = f2b(ev.y + zv.y);
  hb.z = f2b(ev.z + zv.z); hb.w = f2b(ev.w + zv.w);
  *(u16x4*)&h[(long)r * 256 + c] = hb;
}

// ---------------- gemm1: v = lrelu(LN2( lrelu(LN1(h))@w1 + b1 ))  ----------------
// M=64 x N=256 per block. Prologue: LN1+lrelu(h) -> lA (padded 264, 2-way-free).
// B: reg-prefetch -> padded LDS (stride 40). Epilogue: LN2 stats overlaid on lA region.

__global__ __launch_bounds__(256) void gemm1_k(
    const u16* __restrict__ h, const u16* __restrict__ WT,
    const float* __restrict__ lnAg, const float* __restrict__ lnAb,
    const float* __restrict__ bias,
    const float* __restrict__ lnBg, const float* __restrict__ lnBb,
    u16* __restrict__ V)
{
  __shared__ __align__(16) u16 sm[64 * 264 + 256 * 40];   // 54272 B
  u16* lA = sm;
  u16* lB = sm + 64 * 264;
  const int tid = threadIdx.x;
  const int lane = tid & 63;
  const int wv = tid >> 6;
  const int wc = wv * 64;
  const int m0 = blockIdx.x * 64;
  const int lr = lane & 15;
  const int quad = lane >> 4;
  const int lq = quad * 8;
  const int rB = tid >> 2;
  const int cB = tid & 3;

  // preload B k-chunk 0
  uint4 bq0 = *(const uint4*)(WT + (long)rB * 256 + cB * 8);
  uint4 bq1 = *(const uint4*)(WT + (long)(rB + 64) * 256 + cB * 8);
  uint4 bq2 = *(const uint4*)(WT + (long)(rB + 128) * 256 + cB * 8);
  uint4 bq3 = *(const uint4*)(WT + (long)(rB + 192) * 256 + cB * 8);

  // prologue: LN1 + lrelu of 16 rows per wave -> lA
  {
    float4 gv = *(const float4*)&lnAg[lane * 4];
    float4 bv = *(const float4*)&lnAb[lane * 4];
    #pragma unroll 4
    for (int it = 0; it < 16; ++it) {
      int row = wv * 16 + it;
      u16x4 hv = *(const u16x4*)&h[(long)(m0 + row) * 256 + lane * 4];
      float v0 = b2f(hv.x), v1 = b2f(hv.y), v2 = b2f(hv.z), v3 = b2f(hv.w);
      float s = v0 + v1 + v2 + v3;
      float q = v0 * v0 + v1 * v1 + v2 * v2 + v3 * v3;
      #pragma unroll
      for (int o = 1; o < 64; o <<= 1) { s += __shfl_xor(s, o); q += __shfl_xor(q, o); }
      float mu = s * 0.00390625f;
      float var = q * 0.00390625f - mu * mu;
      float rs = rsqrtf(var + 1e-5f);
      float y0 = (v0 - mu) * rs * gv.x + bv.x; y0 = y0 >= 0.f ? y0 : 0.01f * y0;
      float y1 = (v1 - mu) * rs * gv.y + bv.y; y1 = y1 >= 0.f ? y1 : 0.01f * y1;
      float y2 = (v2 - mu) * rs * gv.z + bv.z; y2 = y2 >= 0.f ? y2 : 0.01f * y2;
      float y3 = (v3 - mu) * rs * gv.w + bv.w; y3 = y3 >= 0.f ? y3 : 0.01f * y3;
      u16x4 ov; ov.x = f2b(y0); ov.y = f2b(y1); ov.z = f2b(y2); ov.w = f2b(y3);
      *(u16x4*)&lA[row * 264 + lane * 4] = ov;
    }
  }

  f32x4 acc[4][4];
  #pragma unroll
  for (int i = 0; i < 4; ++i)
    #pragma unroll
    for (int j = 0; j < 4; ++j) {
      acc[i][j][0] = 0.f; acc[i][j][1] = 0.f; acc[i][j][2] = 0.f; acc[i][j][3] = 0.f;
    }

  for (int kt = 0; kt < 8; ++kt) {
    __syncthreads();                     // lA ready (kt=0) / lB reads done (kt>0)
    *(uint4*)&lB[rB * 40 + cB * 8] = bq0;
    *(uint4*)&lB[(rB + 64) * 40 + cB * 8] = bq1;
    *(uint4*)&lB[(rB + 128) * 40 + cB * 8] = bq2;
    *(uint4*)&lB[(rB + 192) * 40 + cB * 8] = bq3;
    __syncthreads();
    if (kt < 7) {
      const u16* src = WT + (kt + 1) * 32 + cB * 8;
      bq0 = *(const uint4*)(src + (long)rB * 256);
      bq1 = *(const uint4*)(src + (long)(rB + 64) * 256);
      bq2 = *(const uint4*)(src + (long)(rB + 128) * 256);
      bq3 = *(const uint4*)(src + (long)(rB + 192) * 256);
    }
    short8 af[4], bfr[4];
    #pragma unroll
    for (int mt = 0; mt < 4; ++mt)
      af[mt] = *(const short8*)&lA[(mt * 16 + lr) * 264 + kt * 32 + lq];
    #pragma unroll
    for (int nt = 0; nt < 4; ++nt)
      bfr[nt] = *(const short8*)&lB[(wc + nt * 16 + lr) * 40 + lq];
    #pragma unroll
    for (int mt = 0; mt < 4; ++mt)
      #pragma unroll
      for (int nt = 0; nt < 4; ++nt)
        acc[mt][nt] = __builtin_amdgcn_mfma_f32_16x16x32_bf16(af[mt], bfr[nt], acc[mt][nt], 0, 0, 0);
  }
  __syncthreads();                       // all lA/lB reads done; overlay stats on sm

  float* pS  = (float*)sm;               // [64][4]
  float* pQ  = pS + 256;                 // [64][4]
  float* muA = pQ + 256;                 // [64]
  float* rsA = muA + 64;                 // [64]

  float biasv[4], gv2[4], bv2[4];
  #pragma unroll
  for (int nt = 0; nt < 4; ++nt) {
    int n = wc + nt * 16 + lr;
    biasv[nt] = bias[n]; gv2[nt] = lnBg[n]; bv2[nt] = lnBb[n];
  }
  #pragma unroll
  for (int mt = 0; mt < 4; ++mt)
    #pragma unroll
    for (int r = 0; r < 4; ++r) {
      float s = 0.f, q = 0.f;
      #pragma unroll
      for (int nt = 0; nt < 4; ++nt) {
        float v = acc[mt][nt][r] + biasv[nt];
        acc[mt][nt][r] = v;
        s += v; q += v * v;
      }
      #pragma unroll
      for (int o = 1; o < 16; o <<= 1) { s += __shfl_xor(s, o); q += __shfl_xor(q, o); }
      if (lr == 0) {
        int row = mt * 16 + quad * 4 + r;
        pS[row * 4 + wv] = s; pQ[row * 4 + wv] = q;
      }
    }
  __syncthreads();
  if (tid < 64) {
    float S = pS[tid * 4] + pS[tid * 4 + 1] + pS[tid * 4 + 2] + pS[tid * 4 + 3];
    float Q = pQ[tid * 4] + pQ[tid * 4 + 1] + pQ[tid * 4 + 2] + pQ[tid * 4 + 3];
    float mu = S * 0.00390625f;
    float var = Q * 0.00390625f - mu * mu;
    muA[tid] = mu; rsA[tid] = rsqrtf(var + 1e-5f);
  }
  __syncthreads();
  #pragma unroll
  for (int mt = 0; mt < 4; ++mt)
    #pragma unroll
    for (int r = 0; r < 4; ++r) {
      int row = mt * 16 + quad * 4 + r;
      float mu = muA[row], rs = rsA[row];
      #pragma unroll
      for (int nt = 0; nt < 4; ++nt) {
        float y = (acc[mt][nt][r] - mu) * rs * gv2[nt] + bv2[nt];
        y = y >= 0.f ? y : 0.01f * y;
        V[(long)(m0 + row) * 256 + wc + nt * 16 + lr] = f2b(y);
      }
    }
}

// ---------------- dil: p = lrelu(LN3( shift(v,d)@wd0 + v@wd1 + bd )) ----------------
// A streamed from global with per-lane causal zero-clamp; B (K=512) reg-prefetch -> padded LDS.

__global__ __launch_bounds__(256) void dil_k(
    const u16* __restrict__ V, const u16* __restrict__ WT, int dil,
    const float* __restrict__ bias, const float* __restrict__ lng, const float* __restrict__ lnb,
    u16* __restrict__ P)
{
  __shared__ __align__(16) u16 lB[256 * 40];
  __shared__ float pS[256], pQ[256], muA[64], rsA[64];
  const int tid = threadIdx.x;
  const int lane = tid & 63;
  const int wv = tid >> 6;
  const int wc = wv * 64;
  const int m0 = blockIdx.x * 64;
  const int lr = lane & 15;
  const int quad = lane >> 4;
  const int lq = quad * 8;
  const int rB = tid >> 2;
  const int cB = tid & 3;

  uint4 bq0 = *(const uint4*)(WT + (long)rB * 512 + cB * 8);
  uint4 bq1 = *(const uint4*)(WT + (long)(rB + 64) * 512 + cB * 8);
  uint4 bq2 = *(const uint4*)(WT + (long)(rB + 128) * 512 + cB * 8);
  uint4 bq3 = *(const uint4*)(WT + (long)(rB + 192) * 512 + cB * 8);

  f32x4 acc[4][4];
  #pragma unroll
  for (int i = 0; i < 4; ++i)
    #pragma unroll
    for (int j = 0; j < 4; ++j) {
      acc[i][j][0] = 0.f; acc[i][j][1] = 0.f; acc[i][j][2] = 0.f; acc[i][j][3] = 0.f;
    }

  const short8 zfrag = {0, 0, 0, 0, 0, 0, 0, 0};
  for (int kt = 0; kt < 16; ++kt) {
    const int kk = (kt & 7) * 32;
    const bool tap0 = (kt < 8);
    short8 af[4];
    #pragma unroll
    for (int mt = 0; mt < 4; ++mt) {
      int m = m0 + mt * 16 + lr;
      int s = m & 511;
      int r = (tap0 && s >= dil) ? (m - dil) : m;
      af[mt] = *(const short8*)(V + (long)r * 256 + kk + lq);
      if (tap0 && s < dil) af[mt] = zfrag;
    }
    __syncthreads();
    *(uint4*)&lB[rB * 40 + cB * 8] = bq0;
    *(uint4*)&lB[(rB + 64) * 40 + cB * 8] = bq1;
    *(uint4*)&lB[(rB + 128) * 40 + cB * 8] = bq2;
    *(uint4*)&lB[(rB + 192) * 40 + cB * 8] = bq3;
    __syncthreads();
    if (kt < 15) {
      const u16* src = WT + (kt + 1) * 32 + cB * 8;
      bq0 = *(const uint4*)(src + (long)rB * 512);
      bq1 = *(const uint4*)(src + (long)(rB + 64) * 512);
      bq2 = *(const uint4*)(src + (long)(rB + 128) * 512);
      bq3 = *(const uint4*)(src + (long)(rB + 192) * 512);
    }
    short8 bfr[4];
    #pragma unroll
    for (int nt = 0; nt < 4; ++nt)
      bfr[nt] = *(const short8*)&lB[(wc + nt * 16 + lr) * 40 + lq];
    #pragma unroll
    for (int mt = 0; mt < 4; ++mt)
      #pragma unroll
      for (int nt = 0; nt < 4; ++nt)
        acc[mt][nt] = __builtin_amdgcn_mfma_f32_16x16x32_bf16(af[mt], bfr[nt], acc[mt][nt], 0, 0, 0);
  }

  // epilogue: bias + LN3 + lrelu
  float biasv[4], gv2[4], bv2[4];
  #pragma unroll
  for (int nt = 0; nt < 4; ++nt) {
    int n = wc + nt * 16 + lr;
    biasv[nt] = bias[n]; gv2[nt] = lng[n]; bv2[nt] = lnb[n];
  }
  #pragma unroll
  for (int mt = 0; mt < 4; ++mt)
    #pragma unroll
    for (int r = 0; r < 4; ++r) {
      float s = 0.f, q = 0.f;
      #pragma unroll
      for (int nt = 0; nt < 4; ++nt) {
        float v = acc[mt][nt][r] + biasv[nt];
        acc[mt][nt][r] = v;
        s += v; q += v * v;
      }
      #pragma unroll
      for (int o = 1; o < 16; o <<= 1) { s += __shfl_xor(s, o); q += __shfl_xor(q, o); }
      if (lr == 0) {
        int row = mt * 16 + quad * 4 + r;
        pS[row * 4 + wv] = s; pQ[row * 4 + wv] = q;
      }
    }
  __syncthreads();
  if (tid < 64) {
    float S = pS[tid * 4] + pS[tid * 4 + 1] + pS[tid * 4 + 2] + pS[tid * 4 + 3];
    float Q = pQ[tid * 4] + pQ[tid * 4 + 1] + pQ[tid * 4 + 2] + pQ[tid * 4 + 3];
    float mu = S * 0.00390625f;
    float var = Q * 0.00390625f - mu * mu;
    muA[tid] = mu; rsA[tid] = rsqrtf(var + 1e-5f);
  }
  __syncthreads();
  #pragma unroll
  for (int mt = 0; mt < 4; ++mt)
    #pragma unroll
    for (int r = 0; r < 4; ++r) {
      int row = mt * 16 + quad * 4 + r;
      float mu = muA[row], rs = rsA[row];
      #pragma unroll
      for (int nt = 0; nt < 4; ++nt) {
        float y = (acc[mt][nt][r] - mu) * rs * gv2[nt] + bv2[nt];
        y = y >= 0.f ? y : 0.01f * y;
        P[(long)(m0 + row) * 256 + wc + nt * 16 + lr] = f2b(y);
      }
    }
}

// ---------------- gate: h = (P@we+be) * sigmoid(P@wg+bg) + h  (no LN here) ----------------

__global__ __launch_bounds__(256, 2) void gate_k(
    const u16* __restrict__ P, const u16* __restrict__ WTe, const u16* __restrict__ WTg,
    const float* __restrict__ be, const float* __restrict__ bg, u16* __restrict__ h)
{
  __shared__ __align__(16) u16 lBe[256 * 40];
  __shared__ __align__(16) u16 lBg[256 * 40];
  const int tid = threadIdx.x;
  const int lane = tid & 63;
  const int wv = tid >> 6;
  const int wc = wv * 64;
  const int m0 = blockIdx.x * 64;
  const int lr = lane & 15;
  const int quad = lane >> 4;
  const int lq = quad * 8;
  const int rB = tid >> 2;
  const int cB = tid & 3;

  uint4 be0 = *(const uint4*)(WTe + (long)rB * 256 + cB * 8);
  uint4 be1 = *(const uint4*)(WTe + (long)(rB + 64) * 256 + cB * 8);
  uint4 be2 = *(const uint4*)(WTe + (long)(rB + 128) * 256 + cB * 8);
  uint4 be3 = *(const uint4*)(WTe + (long)(rB + 192) * 256 + cB * 8);
  uint4 bg0 = *(const uint4*)(WTg + (long)rB * 256 + cB * 8);
  uint4 bg1 = *(const uint4*)(WTg + (long)(rB + 64) * 256 + cB * 8);
  uint4 bg2 = *(const uint4*)(WTg + (long)(rB + 128) * 256 + cB * 8);
  uint4 bg3 = *(const uint4*)(WTg + (long)(rB + 192) * 256 + cB * 8);

  f32x4 accE[4][4], accG[4][4];
  #pragma unroll
  for (int i = 0; i < 4; ++i)
    #pragma unroll
    for (int j = 0; j < 4; ++j) {
      accE[i][j][0] = 0.f; accE[i][j][1] = 0.f; accE[i][j][2] = 0.f; accE[i][j][3] = 0.f;
      accG[i][j][0] = 0.f; accG[i][j][1] = 0.f; accG[i][j][2] = 0.f; accG[i][j][3] = 0.f;
    }

  for (int kt = 0; kt < 8; ++kt) {
    const int kk = kt * 32;
    short8 af[4];
    #pragma unroll
    for (int mt = 0; mt < 4; ++mt)
      af[mt] = *(const short8*)(P + (long)(m0 + mt * 16 + lr) * 256 + kk + lq);
    __syncthreads();
    *(uint4*)&lBe[rB * 40 + cB * 8] = be0;
    *(uint4*)&lBe[(rB + 64) * 40 + cB * 8] = be1;
    *(uint4*)&lBe[(rB + 128) * 40 + cB * 8] = be2;
    *(uint4*)&lBe[(rB + 192) * 40 + cB * 8] = be3;
    *(uint4*)&lBg[rB * 40 + cB * 8] = bg0;
    *(uint4*)&lBg[(rB + 64) * 40 + cB * 8] = bg1;
    *(uint4*)&lBg[(rB + 128) * 40 + cB * 8] = bg2;
    *(uint4*)&lBg[(rB + 192) * 40 + cB * 8] = bg3;
    __syncthreads();
    if (kt < 7) {
      const u16* se = WTe + (kt + 1) * 32 + cB * 8;
      const u16* sg = WTg + (kt + 1) * 32 + cB * 8;
      be0 = *(const uint4*)(se + (long)rB * 256);
      be1 = *(const uint4*)(se + (long)(rB + 64) * 256);
      be2 = *(const uint4*)(se + (long)(rB + 128) * 256);
      be3 = *(const uint4*)(se + (long)(rB + 192) * 256);
      bg0 = *(const uint4*)(sg + (long)rB * 256);
      bg1 = *(const uint4*)(sg + (long)(rB + 64) * 256);
      bg2 = *(const uint4*)(sg + (long)(rB + 128) * 256);
      bg3 = *(const uint4*)(sg + (long)(rB + 192) * 256);
    }
    short8 bfe[4], bfg[4];
    #pragma unroll
    for (int nt = 0; nt < 4; ++nt) {
      bfe[nt] = *(const short8*)&lBe[(wc + nt * 16 + lr) * 40 + lq];
      bfg[nt] = *(const short8*)&lBg[(wc + nt * 16 + lr) * 40 + lq];
    }
    #pragma unroll
    for (int mt = 0; mt < 4; ++mt)
      #pragma unroll
      for (int nt = 0; nt < 4; ++nt) {
        accE[mt][nt] = __builtin_amdgcn_mfma_f32_16x16x32_bf16(af[mt], bfe[nt], accE[mt][nt], 0, 0, 0);
        accG[mt][nt] = __builtin_amdgcn_mfma_f32_16x16x32_bf16(af[mt], bfg[nt], accG[mt][nt], 0, 0, 0);
      }
  }

  float bev[4], bgv[4];
  #pragma unroll
  for (int nt = 0; nt < 4; ++nt) {
    int n = wc + nt * 16 + lr;
    bev[nt] = be[n]; bgv[nt] = bg[n];
  }
  #pragma unroll
  for (int mt = 0; mt < 4; ++mt)
    #pragma unroll
    for (int r = 0; r < 4; ++r) {
      int row = mt * 16 + quad * 4 + r;
      long off = (long)(m0 + row) * 256;
      #pragma unroll
      for (int nt = 0; nt < 4; ++nt) {
        int n = wc + nt * 16 + lr;
        float e = accE[mt][nt][r] + bev[nt];
        float g = accG[mt][nt][r] + bgv[nt];
        float hv = b2f(h[off + n]);
        float hn = e * (1.f / (1.f + expf(-g))) + hv;
        h[off + n] = f2b(hn);
      }
    }
}

// ---------------- final: MFMA logits [M,32], log_softmax, gather next token ----------------

__global__ __launch_bounds__(256) void final_k(const u16* __restrict__ h, const u16* __restrict__ WTo,
                                               const float* __restrict__ outb, const int* __restrict__ x,
                                               float* __restrict__ out) {
  __shared__ u16 lW[32 * 264];        // row pad +8 u16
  const int tid = threadIdx.x;
  const int lane = tid & 63;
  const int wv = tid >> 6;
  const int mBase = blockIdx.x * 256 + wv * 64;

  #pragma unroll
  for (int j = 0; j < 4; ++j) {
    int chunk = tid + 256 * j;        // 0..1023 chunks of 8 u16
    int v = chunk >> 5, k8 = chunk & 31;
    uint4 w4 = *(const uint4*)(WTo + v * 256 + k8 * 8);
    *(uint4*)&lW[v * 264 + k8 * 8] = w4;
  }
  __syncthreads();

  const int lq = (lane >> 4) * 8;
  const int lr = lane & 15;
  const int quad = lane >> 4;

  f32x4 acc[4][2];
  #pragma unroll
  for (int mt = 0; mt < 4; ++mt) {
    acc[mt][0][0] = 0.f; acc[mt][0][1] = 0.f; acc[mt][0][2] = 0.f; acc[mt][0][3] = 0.f;
    acc[mt][1][0] = 0.f; acc[mt][1][1] = 0.f; acc[mt][1][2] = 0.f; acc[mt][1][3] = 0.f;
  }

  for (int kt = 0; kt < 8; ++kt) {
    short8 bf0 = *(const short8*)&lW[lr * 264 + kt * 32 + lq];
    short8 bf1 = *(const short8*)&lW[(16 + lr) * 264 + kt * 32 + lq];
    #pragma unroll
    for (int mt = 0; mt < 4; ++mt) {
      short8 af = *(const short8*)(h + (long)(mBase + mt * 16 + lr) * 256 + kt * 32 + lq);
      acc[mt][0] = __builtin_amdgcn_mfma_f32_16x16x32_bf16(af, bf0, acc[mt][0], 0, 0, 0);
      acc[mt][1] = __builtin_amdgcn_mfma_f32_16x16x32_bf16(af, bf1, acc[mt][1], 0, 0, 0);
    }
  }

  float ob0 = outb[lr], ob1 = outb[16 + lr];
  #pragma unroll
  for (int mt = 0; mt < 4; ++mt)
    #pragma unroll
    for (int r = 0; r < 4; ++r) {
      int row = mBase + mt * 16 + quad * 4 + r;
      float lo = acc[mt][0][r] + ob0;
      float hi = acc[mt][1][r] + ob1;
      float mx = fmaxf(lo, hi);
      #pragma unroll
      for (int o = 1; o < 16; o <<= 1) mx = fmaxf(mx, __shfl_xor(mx, o));
      float se = expf(lo - mx) + expf(hi - mx);
      #pragma unroll
      for (int o = 1; o < 16; o <<= 1) se += __shfl_xor(se, o);
      int s = row & 511;
      int xa = (s == 511) ? row : (row + 1);
      int tok = x[xa];
      float lg = (tok < 16) ? lo : hi;
      float lp = lg - mx - logf(se);
      if (s != 511 && lr == (tok & 15))
        out[(row >> 9) * 511 + s] = lp;
    }
}

// ---------------- launch ----------------

extern "C" void kernel_launch(void* const* d_in, const int* in_sizes, int n_in,
                              void* d_out, int out_size, void* d_ws, size_t ws_size,
                              hipStream_t stream) {
  const int*   x    = (const int*)d_in[0];
  const float* z    = (const float*)d_in[1];
  const float* emb  = (const float*)d_in[2];
  const float* latW = (const float*)d_in[3];
  const float* latb = (const float*)d_in[4];
  const float* ln1g = (const float*)d_in[5];
  const float* ln1b = (const float*)d_in[6];
  const float* w1   = (const float*)d_in[7];
  const float* b1   = (const float*)d_in[8];
  const float* ln2g = (const float*)d_in[9];
  const float* ln2b = (const float*)d_in[10];
  const float* wd   = (const float*)d_in[11];
  const float* bd   = (const float*)d_in[12];
  const float* ln3g = (const float*)d_in[13];
  const float* ln3b = (const float*)d_in[14];
  const float* we   = (const float*)d_in[15];
  const float* be   = (const float*)d_in[16];
  const float* wg   = (const float*)d_in[17];
  const float* bg   = (const float*)d_in[18];
  const float* outW = (const float*)d_in[19];
  const float* outb = (const float*)d_in[20];

  char* ws = (char*)d_ws;
  u16*   h    = (u16*)(ws + 0);               //  67108864  bf16 residual
  u16*   v    = (u16*)(ws + 67108864);        //  67108864
  u16*   p    = (u16*)(ws + 134217728);       //  67108864
  float* zlat = (float*)(ws + 201326592);     //    262144
  u16*   wT1  = (u16*)(ws + 201588736);       //    917504  [i][n][k]
  u16*   wTd  = (u16*)(ws + 202506240);       //   1835008  [i][n][tap*256+k]
  u16*   wTeg = (u16*)(ws + 204341248);       //   1835008  [i][src][n][k]
  u16*   wTo  = (u16*)(ws + 206176256);       //     16384  [v][k]
  // total 206192640 bytes

  conv_w1_k <<<1792, 256, 0, stream>>>(w1, wT1);
  conv_wd_k <<<3584, 256, 0, stream>>>(wd, wTd);
  conv_weg_k<<<3584, 256, 0, stream>>>(we, wg, wTeg);
  conv_wo_k <<<32, 256, 0, stream>>>(outW, wTo);
  zlat_k    <<<256, 256, 0, stream>>>(z, latW, latb, zlat);
  embed_k   <<<M_DIM / 4, 256, 0, stream>>>(x, emb, zlat, h);

  for (int i = 0; i < NL; ++i) {
    int d = 1 << i;
    gemm1_k<<<M_DIM / 64, 256, 0, stream>>>(
        h, wT1 + i * 65536, ln1g + i * 256, ln1b + i * 256, b1 + i * 256,
        ln2g + i * 256, ln2b + i * 256, v);
    dil_k<<<M_DIM / 64, 256, 0, stream>>>(
        v, wTd + i * 131072, d, bd + i * 256, ln3g + i * 256, ln3b + i * 256, p);
    gate_k<<<M_DIM / 64, 256, 0, stream>>>(
        p, wTeg + i * 131072, wTeg + i * 131072 + 65536, be + i * 256, bg + i * 256, h);
  }

  final_k<<<M_DIM / 256, 256, 0, stream>>>(h, wTo, outb, x, (float*)d_out);
}